// Round 5
// baseline (312.794 us; speedup 1.0000x reference)
//
#include <hip/hip_runtime.h>

// SSIM (32,3,512,512) fp32, 11x11 gaussian sigma=1.5 VALID, scalar mean.
// Fused separable conv: v-pass in registers, 5-ch v-stats in LDS, h-pass in
// registers, SSIM + mean fused.
// R5: kill the grid-quantization tail seen in R4 (occupancy 34%: gen1 ran
// 5 blocks/CU, gen2 ran 1 block/CU for ~half the time).
//  - QR=2 -> LDS 21.1KB -> 6-7 blocks/CU capacity; grid 1536 (=6/CU) is
//    fully resident in ONE generation regardless of 6-vs-7 residency.
//  - phase H remapped to 2 rows x 128 threads x 4 cols: all 256 threads
//    active (QR=3 idled 64 threads every H phase).
//  - stride-1 LDS writes (b64) and reads (b128): canonical conflict-free,
//    XOR swizzle dropped.
//  - rows r0..r0+11 always in [0,512) and bands even-length: no clamps/tails.

namespace {
constexpr int IMG_H = 512, IMG_W = 512;
constexpr int OUT_H = 502, OUT_W = 502;
constexpr int NIMG  = 96;             // B*C
constexpr int RPB   = 32;             // output rows per block (last band: 22)
constexpr int NBAND = 16;
constexpr int QR    = 2;              // output rows per inner iteration
constexpr int BUFW  = 528;            // 132 float4 slots (512 v-stat cols + halo)
constexpr int NTASK = NBAND * NIMG;   // 1536 blocks
constexpr double TOTAL = 24192384.0;  // 96*502*502

// exp(-k^2/4.5), double, normalized at compile time (absmax 0.0 R1-R4)
constexpr double U0 = 0.0038659201;
constexpr double U1 = 0.0285655007;
constexpr double U2 = 0.1353352832366127;
constexpr double U3 = 0.4111122898;
constexpr double U4 = 0.8007374026;
constexpr double SS = 1.0 + 2.0 * (U0 + U1 + U2 + U3 + U4);
}

__device__ __forceinline__ float2 f2fma(float w, float2 a, float2 c) {
    return make_float2(fmaf(w, a.x, c.x), fmaf(w, a.y, c.y));
}

__global__ __launch_bounds__(256, 4) void ssim_main(const float* __restrict__ img1,
                                                    const float* __restrict__ img2,
                                                    float* __restrict__ partial)
{
    __shared__ __align__(16) float vrow[QR][5][BUFW];
    __shared__ float red[4];

    const float g[11] = {
        (float)(U0/SS), (float)(U1/SS), (float)(U2/SS), (float)(U3/SS), (float)(U4/SS),
        (float)(1.0/SS),
        (float)(U4/SS), (float)(U3/SS), (float)(U2/SS), (float)(U1/SS), (float)(U0/SS)
    };
    constexpr float C1 = 1e-4f, C2 = 9e-4f;

    const int t   = threadIdx.x;
    const int z   = blockIdx.y;
    const int oy0 = blockIdx.x * RPB;
    const int row_end = min(oy0 + RPB, OUT_H);   // band length always even

    const float* p1 = img1 + (size_t)z * (IMG_H * IMG_W);
    const float* p2 = img2 + (size_t)z * (IMG_H * IMG_W);

    // phase-V: thread owns input cols 2t, 2t+1 -> float index 2t (stride-1 b64)
    const int woff = 2 * t;

    // phase-H: hq = row (t>>7, 0..1), u = 4-col group (t&127), cols 4u..4u+3
    const int hq = t >> 7;
    const int u  = t & 127;
    const int cb = u << 2;

    float local = 0.f;

    for (int r0 = oy0; r0 < row_end; r0 += QR) {
        // ------------- phase V: vertical 11-tap conv, registers -------------
        // rows r0..r0+11 (always within [0,512))
        float2 xr[12], yr[12];
        #pragma unroll
        for (int j = 0; j < 12; ++j) {
            xr[j] = *(const float2*)(p1 + (size_t)(r0 + j) * IMG_W + 2 * t);
            yr[j] = *(const float2*)(p2 + (size_t)(r0 + j) * IMG_W + 2 * t);
        }
        float2 vm1[2], vm2[2], v11[2], v22[2], v12[2];
        #pragma unroll
        for (int q = 0; q < 2; ++q) {
            vm1[q] = make_float2(0.f, 0.f); vm2[q] = make_float2(0.f, 0.f);
            v11[q] = make_float2(0.f, 0.f); v22[q] = make_float2(0.f, 0.f);
            v12[q] = make_float2(0.f, 0.f);
        }
        #pragma unroll
        for (int j = 0; j < 12; ++j) {
            float2 x = xr[j], y = yr[j];
            float2 xx = make_float2(x.x * x.x, x.y * x.y);
            float2 yy = make_float2(y.x * y.x, y.y * y.y);
            float2 xy = make_float2(x.x * y.x, x.y * y.y);
            if (j < 11) {                       // row r0, taps 0..10
                float w = g[j];
                vm1[0] = f2fma(w, x,  vm1[0]);
                vm2[0] = f2fma(w, y,  vm2[0]);
                v11[0] = f2fma(w, xx, v11[0]);
                v22[0] = f2fma(w, yy, v22[0]);
                v12[0] = f2fma(w, xy, v12[0]);
            }
            if (j >= 1) {                       // row r0+1, taps 0..10 on rows 1..11
                float w = g[j - 1];
                vm1[1] = f2fma(w, x,  vm1[1]);
                vm2[1] = f2fma(w, y,  vm2[1]);
                v11[1] = f2fma(w, xx, v11[1]);
                v22[1] = f2fma(w, yy, v22[1]);
                v12[1] = f2fma(w, xy, v12[1]);
            }
        }
        __syncthreads();   // previous iteration's phase-H reads complete
        #pragma unroll
        for (int q = 0; q < 2; ++q) {
            *(float2*)&vrow[q][0][woff] = vm1[q];
            *(float2*)&vrow[q][1][woff] = vm2[q];
            *(float2*)&vrow[q][2][woff] = v11[q];
            *(float2*)&vrow[q][3][woff] = v22[q];
            *(float2*)&vrow[q][4][woff] = v12[q];
        }
        __syncthreads();

        // ------------- phase H: horizontal 11-tap conv + SSIM -------------
        const int rr = r0 + hq;
        if (rr < row_end) {
            float aa[5][4];
            #pragma unroll
            for (int ch = 0; ch < 5; ++ch) {
                const float* bc = &vrow[hq][ch][0];
                float f[16];
                #pragma unroll
                for (int k = 0; k < 4; ++k) {
                    float4 v = *(const float4*)(bc + ((u + k) << 2));  // stride-1 slots
                    f[4*k+0] = v.x; f[4*k+1] = v.y; f[4*k+2] = v.z; f[4*k+3] = v.w;
                }
                #pragma unroll
                for (int j = 0; j < 4; ++j) {
                    float s = 0.f;
                    #pragma unroll
                    for (int k = 0; k < 11; ++k) s = fmaf(g[k], f[j + k], s);
                    aa[ch][j] = s;
                }
            }
            #pragma unroll
            for (int j = 0; j < 4; ++j) {
                if (cb + j < OUT_W) {
                    float mu1 = aa[0][j], mu2 = aa[1][j];
                    float mu11 = mu1 * mu1, mu22 = mu2 * mu2, mu12 = mu1 * mu2;
                    float s1  = aa[2][j] - mu11;
                    float s2  = aa[3][j] - mu22;
                    float s12 = aa[4][j] - mu12;
                    float num = fmaf(2.f, mu12, C1) * fmaf(2.f, s12, C2);
                    float den = (mu11 + mu22 + C1) * (s1 + s2 + C2);
                    float rc  = __builtin_amdgcn_rcpf(den);
                    rc = rc * fmaf(-den, rc, 2.f);          // one Newton step
                    local += num * rc;
                }
            }
        }
    }

    // ---------- reduction: wave shuffle -> LDS -> one store per block ----------
    #pragma unroll
    for (int off = 32; off > 0; off >>= 1) local += __shfl_down(local, off, 64);
    if ((t & 63) == 0) red[t >> 6] = local;
    __syncthreads();
    if (t == 0)
        partial[blockIdx.y * NBAND + blockIdx.x] = red[0] + red[1] + red[2] + red[3];
}

__global__ void ssim_fin(const float* __restrict__ partial, float* __restrict__ out)
{
    __shared__ double sd[256];
    double sum = 0.0;
    for (int i = threadIdx.x; i < NTASK; i += 256) sum += (double)partial[i];
    sd[threadIdx.x] = sum;
    __syncthreads();
    for (int w = 128; w > 0; w >>= 1) {
        if (threadIdx.x < w) sd[threadIdx.x] += sd[threadIdx.x + w];
        __syncthreads();
    }
    if (threadIdx.x == 0) out[0] = (float)(sd[0] / TOTAL);
}

extern "C" void kernel_launch(void* const* d_in, const int* in_sizes, int n_in,
                              void* d_out, int out_size, void* d_ws, size_t ws_size,
                              hipStream_t stream)
{
    (void)in_sizes; (void)n_in; (void)out_size; (void)ws_size;
    const float* img1 = (const float*)d_in[0];
    const float* img2 = (const float*)d_in[1];
    float* partial = (float*)d_ws;

    hipLaunchKernelGGL(ssim_main, dim3(NBAND, NIMG), dim3(256), 0, stream,
                       img1, img2, partial);
    hipLaunchKernelGGL(ssim_fin, dim3(1), dim3(256), 0, stream,
                       partial, (float*)d_out);
}

// Round 6
// 278.436 us; speedup vs baseline: 1.1234x; 1.1234x over previous
//
#include <hip/hip_runtime.h>

// SSIM (32,3,512,512) fp32, 11x11 gaussian sigma=1.5 VALID, scalar mean.
// Fused separable conv: v-pass in registers, 5-ch v-stats in LDS, h-pass
// 8 cols/thread (R4 pattern - measured 5x fewer LDS conflicts than the
// stride-1-float4 R5 pattern), SSIM + mean fused.
// R6: (a) NBAND=10 (RPB=51) -> grid 960 = 3.75 blocks/CU < residency
// capacity (5 by LDS 31.7KB) -> ONE generation, kills R4's tail that held
// time-avg occupancy at 34%. (b) slot swizzle = bit0<->bit3 swap: every 8
// consecutive lanes fill one 128B LDS window exactly for both k parities.

namespace {
constexpr int IMG_H = 512, IMG_W = 512;
constexpr int OUT_H = 502, OUT_W = 502;
constexpr int NIMG  = 96;             // B*C
constexpr int RPB   = 51;             // output rows per block (= 17*QR; last band 43)
constexpr int NBAND = 10;
constexpr int QR    = 3;              // output rows per inner iteration
constexpr int BUFW  = 528;            // 132 float4 slots (512 v-stat cols + halo)
constexpr int NTASK = NBAND * NIMG;   // 960 blocks
constexpr double TOTAL = 24192384.0;  // 96*502*502

// exp(-k^2/4.5), double, normalized at compile time (absmax 0.0 R1-R5)
constexpr double U0 = 0.0038659201;
constexpr double U1 = 0.0285655007;
constexpr double U2 = 0.1353352832366127;
constexpr double U3 = 0.4111122898;
constexpr double U4 = 0.8007374026;
constexpr double SS = 1.0 + 2.0 * (U0 + U1 + U2 + U3 + U4);
}

// swap bit0 <-> bit3 of the float4-slot index (self-inverse bijection)
__device__ __forceinline__ int sw(int s) {
    int b = (s ^ (s >> 3)) & 1;
    return s ^ b ^ (b << 3);
}

__device__ __forceinline__ float2 f2fma(float w, float2 a, float2 c) {
    return make_float2(fmaf(w, a.x, c.x), fmaf(w, a.y, c.y));
}

__global__ __launch_bounds__(256, 4) void ssim_main(const float* __restrict__ img1,
                                                    const float* __restrict__ img2,
                                                    float* __restrict__ partial)
{
    __shared__ __align__(16) float vrow[QR][5][BUFW];
    __shared__ float red[4];

    const float g[11] = {
        (float)(U0/SS), (float)(U1/SS), (float)(U2/SS), (float)(U3/SS), (float)(U4/SS),
        (float)(1.0/SS),
        (float)(U4/SS), (float)(U3/SS), (float)(U2/SS), (float)(U1/SS), (float)(U0/SS)
    };
    constexpr float C1 = 1e-4f, C2 = 9e-4f;

    const int t   = threadIdx.x;
    const int z   = blockIdx.y;
    const int oy0 = blockIdx.x * RPB;
    const int row_end = min(oy0 + RPB, OUT_H);

    const float* p1 = img1 + (size_t)z * (IMG_H * IMG_W);
    const float* p2 = img2 + (size_t)z * (IMG_H * IMG_W);

    // phase-V: thread owns input cols 2t, 2t+1
    const int woff = (sw(t >> 1) << 2) + ((t & 1) << 1);

    // phase-H: hq = row-in-group (t>>6, rows 0..2 active), 8-col group at cb
    const int hq = t >> 6;
    const int hl = t & 63;
    const int cb = hl << 3;
    int roff[5];
    #pragma unroll
    for (int k = 0; k < 5; ++k) roff[k] = sw((cb >> 2) + k) << 2;

    float local = 0.f;

    for (int r0 = oy0; r0 < row_end; r0 += QR) {
        // ------------- phase V: vertical 11-tap conv, registers -------------
        float2 xr[QR + 10], yr[QR + 10];
        #pragma unroll
        for (int j = 0; j < QR + 10; ++j) {
            int row = r0 + j;
            row = row < IMG_H ? row : IMG_H - 1;   // last-band tail clamp; unused by valid outputs
            xr[j] = *(const float2*)(p1 + (size_t)row * IMG_W + 2 * t);
            yr[j] = *(const float2*)(p2 + (size_t)row * IMG_W + 2 * t);
        }
        float2 vm1[QR], vm2[QR], v11[QR], v22[QR], v12[QR];
        #pragma unroll
        for (int q = 0; q < QR; ++q) {
            vm1[q] = make_float2(0.f, 0.f); vm2[q] = make_float2(0.f, 0.f);
            v11[q] = make_float2(0.f, 0.f); v22[q] = make_float2(0.f, 0.f);
            v12[q] = make_float2(0.f, 0.f);
        }
        #pragma unroll
        for (int j = 0; j < QR + 10; ++j) {
            float2 x = xr[j], y = yr[j];
            float2 xx = make_float2(x.x * x.x, x.y * x.y);
            float2 yy = make_float2(y.x * y.x, y.y * y.y);
            float2 xy = make_float2(x.x * y.x, x.y * y.y);
            #pragma unroll
            for (int q = 0; q < QR; ++q) {
                int k = j - q;
                if (k >= 0 && k < 11) {
                    float w = g[k];
                    vm1[q] = f2fma(w, x,  vm1[q]);
                    vm2[q] = f2fma(w, y,  vm2[q]);
                    v11[q] = f2fma(w, xx, v11[q]);
                    v22[q] = f2fma(w, yy, v22[q]);
                    v12[q] = f2fma(w, xy, v12[q]);
                }
            }
        }
        __syncthreads();   // previous iteration's phase-H reads complete
        #pragma unroll
        for (int q = 0; q < QR; ++q) {
            *(float2*)&vrow[q][0][woff] = vm1[q];
            *(float2*)&vrow[q][1][woff] = vm2[q];
            *(float2*)&vrow[q][2][woff] = v11[q];
            *(float2*)&vrow[q][3][woff] = v22[q];
            *(float2*)&vrow[q][4][woff] = v12[q];
        }
        __syncthreads();

        // ------------- phase H: horizontal 11-tap conv + SSIM -------------
        const int rr = r0 + hq;
        if (hq < QR && rr < row_end && cb < OUT_W) {
            float aa[5][8];
            #pragma unroll
            for (int ch = 0; ch < 5; ++ch) {
                const float* bc = &vrow[hq][ch][0];
                float f[20];
                #pragma unroll
                for (int k = 0; k < 5; ++k) {
                    float4 v = *(const float4*)(bc + roff[k]);
                    f[4*k+0] = v.x; f[4*k+1] = v.y; f[4*k+2] = v.z; f[4*k+3] = v.w;
                }
                #pragma unroll
                for (int j = 0; j < 8; ++j) {
                    float s = 0.f;
                    #pragma unroll
                    for (int k = 0; k < 11; ++k) s = fmaf(g[k], f[j + k], s);
                    aa[ch][j] = s;
                }
            }
            #pragma unroll
            for (int j = 0; j < 8; ++j) {
                if (cb + j < OUT_W) {
                    float mu1 = aa[0][j], mu2 = aa[1][j];
                    float mu11 = mu1 * mu1, mu22 = mu2 * mu2, mu12 = mu1 * mu2;
                    float s1  = aa[2][j] - mu11;
                    float s2  = aa[3][j] - mu22;
                    float s12 = aa[4][j] - mu12;
                    float num = fmaf(2.f, mu12, C1) * fmaf(2.f, s12, C2);
                    float den = (mu11 + mu22 + C1) * (s1 + s2 + C2);
                    float rc  = __builtin_amdgcn_rcpf(den);
                    rc = rc * fmaf(-den, rc, 2.f);          // one Newton step
                    local += num * rc;
                }
            }
        }
    }

    // ---------- reduction: wave shuffle -> LDS -> one store per block ----------
    #pragma unroll
    for (int off = 32; off > 0; off >>= 1) local += __shfl_down(local, off, 64);
    if ((t & 63) == 0) red[t >> 6] = local;
    __syncthreads();
    if (t == 0)
        partial[blockIdx.y * NBAND + blockIdx.x] = red[0] + red[1] + red[2] + red[3];
}

__global__ void ssim_fin(const float* __restrict__ partial, float* __restrict__ out)
{
    __shared__ double sd[256];
    double sum = 0.0;
    for (int i = threadIdx.x; i < NTASK; i += 256) sum += (double)partial[i];
    sd[threadIdx.x] = sum;
    __syncthreads();
    for (int w = 128; w > 0; w >>= 1) {
        if (threadIdx.x < w) sd[threadIdx.x] += sd[threadIdx.x + w];
        __syncthreads();
    }
    if (threadIdx.x == 0) out[0] = (float)(sd[0] / TOTAL);
}

extern "C" void kernel_launch(void* const* d_in, const int* in_sizes, int n_in,
                              void* d_out, int out_size, void* d_ws, size_t ws_size,
                              hipStream_t stream)
{
    (void)in_sizes; (void)n_in; (void)out_size; (void)ws_size;
    const float* img1 = (const float*)d_in[0];
    const float* img2 = (const float*)d_in[1];
    float* partial = (float*)d_ws;

    hipLaunchKernelGGL(ssim_main, dim3(NBAND, NIMG), dim3(256), 0, stream,
                       img1, img2, partial);
    hipLaunchKernelGGL(ssim_fin, dim3(1), dim3(256), 0, stream,
                       partial, (float*)d_out);
}